// Round 1
// baseline (382.636 us; speedup 1.0000x reference)
//
#include <hip/hip_runtime.h>
#include <hip/hip_bf16.h>

typedef unsigned short u16;
using bf16x8 = __bf16 __attribute__((ext_vector_type(8)));
using f32x4  = float  __attribute__((ext_vector_type(4)));

#define BB 4
#define TT 4096
#define DD 1024
#define MROWS (BB*TT)   /* 16384 */
#define CT 64           /* scan chunk length */
#define NC (TT/CT)      /* 64 chunks */

__device__ __forceinline__ float sigm(float x) { return 1.0f / (1.0f + __expf(-x)); }
__device__ __forceinline__ u16 f2bf(float f) {
    __hip_bfloat16 h = __float2bfloat16(f);
    return *reinterpret_cast<u16*>(&h);
}
__device__ __forceinline__ float bf2f(u16 u) { return __uint_as_float(((unsigned)u) << 16); }

// async 16B global->LDS (direct-to-shared DMA; LDS dest must be wave-uniform base + lane*16)
__device__ __forceinline__ void async_cp16(const u16* g, u16* l) {
    __builtin_amdgcn_global_load_lds(
        (const __attribute__((address_space(1))) unsigned int*)g,
        (__attribute__((address_space(3))) unsigned int*)l, 16, 0, 0);
}

// ---------------------------------------------------------------- converts
__global__ __launch_bounds__(256) void conv_x_kernel(const float* __restrict__ s,
                                                     u16* __restrict__ d) {
    size_t i = (size_t)blockIdx.x * 256 + threadIdx.x;   // one float4 per thread
    float4 v = *(const float4*)(s + i * 4);
    ushort4 u;
    u.x = f2bf(v.x); u.y = f2bf(v.y); u.z = f2bf(v.z); u.w = f2bf(v.w);
    *(ushort4*)(d + i * 4) = u;
}

__global__ __launch_bounds__(256) void conv_w4_kernel(const float* __restrict__ w0,
                                                      const float* __restrict__ w1,
                                                      const float* __restrict__ w2,
                                                      const float* __restrict__ w3,
                                                      u16* __restrict__ dst) {
    int i = blockIdx.x * 256 + threadIdx.x;  // 0 .. 4*2^18-1 float4s
    int sel = i >> 18;                       // 2^18 float4 per 1024x1024 weight
    int off = i & 262143;
    const float* s = (sel == 0) ? w0 : (sel == 1) ? w1 : (sel == 2) ? w2 : w3;
    float4 v = *(const float4*)(s + (size_t)off * 4);
    ushort4 u;
    u.x = f2bf(v.x); u.y = f2bf(v.y); u.z = f2bf(v.z); u.w = f2bf(v.w);
    *(ushort4*)(dst + ((size_t)sel << 20) + (size_t)off * 4) = u;
}

// ---------------------------------------------------------------- GEMM
// C[m][n] = sum_k A[m][k] * W[n][k], A:[M,K] bf16 row-major, W:[N,K] bf16 row-major.
// 128x128 tile, BK=64, 4 waves (2x2), each wave 64x64 via 4x4 mfma_f32_16x16x32_bf16.
// LDS XOR-swizzle: physical granule p of row m holds logical k-granule p^(m&7)
// (swizzle applied on the GLOBAL address side so global_load_lds's
//  wave-uniform-base+lane*16 LDS pattern is contiguous). R0: 0 bank conflicts.
#define BM 128
#define BN 128
#define BK 64

template <typename OutT>
__global__ __launch_bounds__(256, 2)
void gemm_bf16_bt(const u16* __restrict__ Ag, const u16* __restrict__ Bg, int K,
                  OutT* __restrict__ P0, OutT* __restrict__ P1, OutT* __restrict__ P2) {
    __shared__ u16 As[BM * BK];
    __shared__ u16 Bs[BN * BK];

    const int tid  = threadIdx.x;
    const int lane = tid & 63;
    const int wid  = tid >> 6;
    const int wm   = wid >> 1;      // wave row 0..1
    const int wn   = wid & 1;       // wave col 0..1
    const int lr   = lane & 15;
    const int lq   = lane >> 4;

    const long bM  = (long)blockIdx.y * BM;
    const long bN0 = (long)blockIdx.x * BN;

    const f32x4 zero = {0.f, 0.f, 0.f, 0.f};
    f32x4 acc[4][4];
#pragma unroll
    for (int i = 0; i < 4; i++)
#pragma unroll
        for (int j = 0; j < 4; j++) acc[i][j] = zero;

    for (int kt = 0; kt < K; kt += BK) {
        __syncthreads();
#pragma unroll
        for (int j = 0; j < 4; j++) {
            const int G  = j * 256 + tid;     // LDS granule = wave_base + lane (contiguous)
            const int m  = G >> 3;            // row 0..127
            const int p  = G & 7;             // physical granule
            const int gk = p ^ (m & 7);       // logical k-granule (swizzle on global side)
            async_cp16(Ag + (bM + m) * K + kt + gk * 8, &As[G * 8]);
            async_cp16(Bg + (bN0 + m) * K + kt + gk * 8, &Bs[G * 8]);
        }
        __syncthreads();   // compiler emits s_waitcnt vmcnt(0) before s_barrier
#pragma unroll
        for (int kk = 0; kk < BK / 32; kk++) {
            bf16x8 av[4], bv[4];
#pragma unroll
            for (int f = 0; f < 4; f++) {
                const int am = wm * 64 + f * 16 + lr;
                const int ag = (kk * 4 + lq) ^ (am & 7);
                av[f] = *(const bf16x8*)(&As[am * 64 + ag * 8]);
                const int bn = wn * 64 + f * 16 + lr;
                const int bg = (kk * 4 + lq) ^ (bn & 7);
                bv[f] = *(const bf16x8*)(&Bs[bn * 64 + bg * 8]);
            }
#pragma unroll
            for (int i = 0; i < 4; i++)
#pragma unroll
                for (int j = 0; j < 4; j++)
                    acc[i][j] = __builtin_amdgcn_mfma_f32_16x16x32_bf16(av[i], bv[j],
                                                                        acc[i][j], 0, 0, 0);
        }
    }

    const int pl = (int)(bN0 >> 10);   // BN=128 divides 1024 -> whole block in one plane
    OutT* P = (pl == 0) ? P0 : ((pl == 1) ? P1 : P2);
    const int cn = (int)(bN0 & 1023);
#pragma unroll
    for (int i = 0; i < 4; i++) {
        const long m0 = bM + wm * 64 + i * 16 + lq * 4;
#pragma unroll
        for (int j = 0; j < 4; j++) {
            const int n = cn + wn * 64 + j * 16 + lr;
#pragma unroll
            for (int r = 0; r < 4; r++) {
                if constexpr (sizeof(OutT) == 2)
                    P[(m0 + r) * 1024 + n] = f2bf(acc[i][j][r]);
                else
                    P[(m0 + r) * 1024 + n] = acc[i][j][r];
            }
        }
    }
}

// ---------------------------------------------------------------- chunked scan
// h_t = f_t * h_{t-1} + silu(i_t)*(1-f_t),  f = sigmoid(f_pre); planes are bf16
// pass1: per-chunk (F,I) aggregates. 4 d's per thread, ushort4 (8B) loads (G13).
__global__ __launch_bounds__(256) void scan_pass1(const u16* __restrict__ ip,
                                                  const u16* __restrict__ fp,
                                                  float* __restrict__ Fc,
                                                  float* __restrict__ Ic) {
    const int tid = blockIdx.x * 256 + threadIdx.x;  // B*NC*D/4 = 65536 threads
    const int d4  = tid & 255;                       // d/4
    const int c   = (tid >> 8) & (NC - 1);
    const int b   = tid >> 14;
    size_t base = ((size_t)(b * TT + c * CT) << 10) + (size_t)d4 * 4;
    float F[4] = {1.f, 1.f, 1.f, 1.f};
    float I[4] = {0.f, 0.f, 0.f, 0.f};
#pragma unroll 8
    for (int t = 0; t < CT; t++) {
        ushort4 fu = *(const ushort4*)(fp + base);
        ushort4 iu = *(const ushort4*)(ip + base);
        base += DD;
        const u16 fa[4] = {fu.x, fu.y, fu.z, fu.w};
        const u16 ia[4] = {iu.x, iu.y, iu.z, iu.w};
#pragma unroll
        for (int j = 0; j < 4; j++) {
            float f  = sigm(bf2f(fa[j]));
            float iv = bf2f(ia[j]);
            float v  = iv * sigm(iv) * (1.f - f);
            I[j] = fmaf(f, I[j], v);
            F[j] *= f;
        }
    }
    const size_t o = (((size_t)(b * NC + c)) << 10) + (size_t)d4 * 4;
    float4 vF = {F[0], F[1], F[2], F[3]};
    float4 vI = {I[0], I[1], I[2], I[3]};
    *(float4*)(Fc + o) = vF;
    *(float4*)(Ic + o) = vI;
}

// pass2: exclusive scan over the 64 chunks via in-wave Kogge-Stone.
// One wave per (b,d); lane = chunk index. combine(prev,cur): F=Fp*F, I=Ip*F+I.
__global__ __launch_bounds__(256) void scan_pass2(const float* __restrict__ Fc,
                                                  const float* __restrict__ Ic,
                                                  float* __restrict__ Hin) {
    const int gtid = blockIdx.x * 256 + threadIdx.x;   // B*D*64 = 262144 threads
    const int lane = gtid & 63;                        // chunk c
    const int w    = gtid >> 6;                        // wave id = (b,d)
    const int b    = w >> 10;
    const int d    = w & 1023;
    const int idx  = ((b * NC + lane) << 10) + d;
    float F = Fc[idx];
    float I = Ic[idx];
#pragma unroll
    for (int s = 1; s < 64; s <<= 1) {
        float Fp = __shfl_up(F, s, 64);
        float Ip = __shfl_up(I, s, 64);
        if (lane >= s) {
            I = fmaf(Ip, F, I);   // use pre-update F
            F *= Fp;
        }
    }
    // exclusive: h entering chunk c = I-aggregate of chunks 0..c-1 (h0 = 0)
    float Hex = __shfl_up(I, 1, 64);
    if (lane == 0) Hex = 0.f;
    Hin[idx] = Hex;
}

__global__ __launch_bounds__(256) void scan_pass3(const u16* __restrict__ ip,
                                                  const u16* __restrict__ fp,
                                                  const float* __restrict__ Hin,
                                                  u16* __restrict__ hout) {
    const int tid = blockIdx.x * 256 + threadIdx.x;  // B*NC*D/4 = 65536 threads
    const int d4  = tid & 255;
    const int c   = (tid >> 8) & (NC - 1);
    const int b   = tid >> 14;
    size_t base = ((size_t)(b * TT + c * CT) << 10) + (size_t)d4 * 4;
    const size_t o = (((size_t)(b * NC + c)) << 10) + (size_t)d4 * 4;
    float4 hv = *(const float4*)(Hin + o);
    float h[4] = {hv.x, hv.y, hv.z, hv.w};
#pragma unroll 8
    for (int t = 0; t < CT; t++) {
        ushort4 fu = *(const ushort4*)(fp + base);
        ushort4 iu = *(const ushort4*)(ip + base);
        const u16 fa[4] = {fu.x, fu.y, fu.z, fu.w};
        const u16 ia[4] = {iu.x, iu.y, iu.z, iu.w};
        ushort4 ou;
        u16 oa[4];
#pragma unroll
        for (int j = 0; j < 4; j++) {
            float f  = sigm(bf2f(fa[j]));
            float iv = bf2f(ia[j]);
            float v  = iv * sigm(iv) * (1.f - f);
            h[j] = fmaf(f, h[j], v);
            oa[j] = f2bf(h[j]);
        }
        ou.x = oa[0]; ou.y = oa[1]; ou.z = oa[2]; ou.w = oa[3];
        *(ushort4*)(hout + base) = ou;
        base += DD;
    }
}

// ---------------------------------------------------------------- RMSNorm * swish(g)
// hin and oout alias (in-place): all h reads happen before the barrier, writes after.
__global__ __launch_bounds__(256) void rmsnorm_gate(const u16* hin,
                                                    const u16* __restrict__ g,
                                                    const float* __restrict__ w,
                                                    u16* oout) {
    const int row = blockIdx.x;
    const int t = threadIdx.x;
    const size_t base = ((size_t)row << 10) + t * 4;
    ushort4 hu = *(const ushort4*)(hin + base);
    float h0 = bf2f(hu.x), h1 = bf2f(hu.y), h2 = bf2f(hu.z), h3 = bf2f(hu.w);
    float ss = h0 * h0 + h1 * h1 + h2 * h2 + h3 * h3;
#pragma unroll
    for (int o = 32; o > 0; o >>= 1) ss += __shfl_down(ss, o);
    __shared__ float red[4];
    if ((t & 63) == 0) red[t >> 6] = ss;
    __syncthreads();
    const float tot = red[0] + red[1] + red[2] + red[3];
    const float rms = rsqrtf(tot * (1.f / 1024.f) + 1e-5f);
    ushort4 gu = *(const ushort4*)(g + base);
    float g0 = bf2f(gu.x), g1 = bf2f(gu.y), g2 = bf2f(gu.z), g3 = bf2f(gu.w);
    float4 wv = *(const float4*)(w + (size_t)t * 4);
    ushort4 ou;
    ou.x = f2bf(h0 * rms * wv.x * g0 * sigm(g0));
    ou.y = f2bf(h1 * rms * wv.y * g1 * sigm(g1));
    ou.z = f2bf(h2 * rms * wv.z * g2 * sigm(g2));
    ou.w = f2bf(h3 * rms * wv.w * g3 * sigm(g3));
    *(ushort4*)(oout + base) = ou;
}

// ---------------------------------------------------------------- launch
extern "C" void kernel_launch(void* const* d_in, const int* in_sizes, int n_in,
                              void* d_out, int out_size, void* d_ws, size_t ws_size,
                              hipStream_t stream) {
    const float* x  = (const float*)d_in[0];
    const float* Wi = (const float*)d_in[1];
    const float* Wf = (const float*)d_in[2];
    const float* Wg = (const float*)d_in[3];
    const float* Wo = (const float*)d_in[4];
    const float* nw = (const float*)d_in[5];
    float* out = (float*)d_out;

    const size_t MB = 1ull << 20;
    char* ws = (char*)d_ws;
    u16*   xo  = (u16*)(ws);              // 32MB: x_bf16, later h_bf16 then o_bf16
    u16*   Wb  = (u16*)(ws + 32 * MB);    // 8MB: [Wi;Wf;Wg;Wo] bf16, K-major rows
    u16*   Pi  = (u16*)(ws + 40 * MB);    // 32MB: i_pre bf16
    u16*   Pf  = (u16*)(ws + 72 * MB);    // 32MB: f_pre bf16
    float* Fc  = (float*)(ws + 104 * MB); // 1MB
    float* Ic  = Fc + BB * NC * DD;       // 1MB
    float* Hin = Ic + BB * NC * DD;       // 1MB
    u16*   g   = (u16*)d_out;             // g plane (bf16) parked in d_out until final GEMM

    conv_x_kernel<<<16384, 256, 0, stream>>>(x, xo);
    conv_w4_kernel<<<4096, 256, 0, stream>>>(Wi, Wf, Wg, Wo, Wb);
    // i_pre / f_pre / g in one GEMM: N=3072
    gemm_bf16_bt<u16><<<dim3(24, 128), 256, 0, stream>>>(xo, Wb, 1024, Pi, Pf, g);
    scan_pass1<<<256, 256, 0, stream>>>(Pi, Pf, Fc, Ic);
    scan_pass2<<<1024, 256, 0, stream>>>(Fc, Ic, Hin);
    scan_pass3<<<256, 256, 0, stream>>>(Pi, Pf, Hin, xo);
    rmsnorm_gate<<<16384, 256, 0, stream>>>(xo, g, nw, xo);
    // out = o @ Wo^T
    gemm_bf16_bt<float><<<dim3(8, 128), 256, 0, stream>>>(xo, Wb + 3ull * 1024 * 1024, 1024,
                                                          out, out, out);
}

// Round 2
// 382.168 us; speedup vs baseline: 1.0012x; 1.0012x over previous
//
#include <hip/hip_runtime.h>
#include <hip/hip_bf16.h>

typedef unsigned short u16;
using bf16x8 = __bf16 __attribute__((ext_vector_type(8)));
using f32x4  = float  __attribute__((ext_vector_type(4)));

#define BB 4
#define TT 4096
#define DD 1024
#define MROWS (BB*TT)   /* 16384 */
#define CT 64           /* scan chunk length */
#define NC (TT/CT)      /* 64 chunks */

__device__ __forceinline__ float sigm(float x) { return 1.0f / (1.0f + __expf(-x)); }
__device__ __forceinline__ u16 f2bf(float f) {
    __hip_bfloat16 h = __float2bfloat16(f);
    return *reinterpret_cast<u16*>(&h);
}
__device__ __forceinline__ float bf2f(u16 u) { return __uint_as_float(((unsigned)u) << 16); }

// async 16B global->LDS (direct-to-shared DMA; LDS dest must be wave-uniform base + lane*16)
__device__ __forceinline__ void async_cp16(const u16* g, u16* l) {
    __builtin_amdgcn_global_load_lds(
        (const __attribute__((address_space(1))) unsigned int*)g,
        (__attribute__((address_space(3))) unsigned int*)l, 16, 0, 0);
}

// ---------------------------------------------------------------- converts
__global__ __launch_bounds__(256) void conv_x_kernel(const float* __restrict__ s,
                                                     u16* __restrict__ d) {
    size_t i = (size_t)blockIdx.x * 256 + threadIdx.x;   // one float4 per thread
    float4 v = *(const float4*)(s + i * 4);
    ushort4 u;
    u.x = f2bf(v.x); u.y = f2bf(v.y); u.z = f2bf(v.z); u.w = f2bf(v.w);
    *(ushort4*)(d + i * 4) = u;
}

__global__ __launch_bounds__(256) void conv_w4_kernel(const float* __restrict__ w0,
                                                      const float* __restrict__ w1,
                                                      const float* __restrict__ w2,
                                                      const float* __restrict__ w3,
                                                      u16* __restrict__ dst) {
    int i = blockIdx.x * 256 + threadIdx.x;  // 0 .. 4*2^18-1 float4s
    int sel = i >> 18;                       // 2^18 float4 per 1024x1024 weight
    int off = i & 262143;
    const float* s = (sel == 0) ? w0 : (sel == 1) ? w1 : (sel == 2) ? w2 : w3;
    float4 v = *(const float4*)(s + (size_t)off * 4);
    ushort4 u;
    u.x = f2bf(v.x); u.y = f2bf(v.y); u.z = f2bf(v.z); u.w = f2bf(v.w);
    *(ushort4*)(dst + ((size_t)sel << 20) + (size_t)off * 4) = u;
}

// ---------------------------------------------------------------- GEMM (256x256 8-phase)
// C[m][n] = sum_k A[m][k] * W[n][k], A:[M,K] bf16 row-major, W:[N,K] bf16 row-major.
// 256x256 tile, BK=64, 8 waves (2Mx4N), per-wave 128x64 via acc[8][4] mfma 16x16x32.
// LDS 128KiB = 2 bufs x (A 32K + B 32K), each operand split into 2 "halves" matching
// the C-quadrant read sets: A-half h = rows with bit6==h, B-half h = rows with bit5==h.
// Per K-tile group of 4 phases (C-quadrants (mh,nh) in order 00,01,10,11):
//   P1 reads A-h0+B-h0, stages A1(c+1); P2 reads B-h1, stages B1(c+1);
//   P3 reads A-h1, stages A0(c+2);      P4 (no reads), stages B0(c+2), vmcnt(4).
// Every staged slot was freed >=1 phase before its stage-issue; vmcnt(4) at P4 retires
// everything up to tile c+1's last half, leaving 2 half-tiles (4 loads) in flight.
// Granule XOR swizzle (phys = logical ^ (row&7)) applied on the GLOBAL address so the
// LDS dest of global_load_lds stays linear; ds_read side XORs back. 0 bank conflicts.
#define G_BM 256
#define G_BN 256
#define G_BK 64

#define READ_A(dst, MH)                                                         \
  { const u16* Ab = &As[(p * 2 + (MH)) << 13];                                  \
    _Pragma("unroll") for (int kk = 0; kk < 2; kk++) {                          \
      const int gsw = (((kk * 4 + lq) ^ lr7) << 3);                             \
      _Pragma("unroll") for (int f = 0; f < 4; f++)                             \
        dst[f][kk] = *(const bf16x8*)(Ab + (wm * 64 + f * 16 + lr) * 64 + gsw); \
    } }
#define READ_B(dst, NH)                                                         \
  { const u16* Bb = &Bs[(p * 2 + (NH)) << 13];                                  \
    _Pragma("unroll") for (int kk = 0; kk < 2; kk++) {                          \
      const int gsw = (((kk * 4 + lq) ^ lr7) << 3);                             \
      _Pragma("unroll") for (int j = 0; j < 2; j++)                             \
        dst[j][kk] = *(const bf16x8*)(Bb + (wn * 32 + j * 16 + lr) * 64 + gsw); \
    } }
#define MFMA16(AV, BV, MH, NH)                                                  \
  { _Pragma("unroll") for (int kk = 0; kk < 2; kk++)                            \
    _Pragma("unroll") for (int f = 0; f < 4; f++)                               \
    _Pragma("unroll") for (int j = 0; j < 2; j++)                               \
      acc[(MH)*4+f][(NH)*2+j] = __builtin_amdgcn_mfma_f32_16x16x32_bf16(        \
          AV[f][kk], BV[j][kk], acc[(MH)*4+f][(NH)*2+j], 0, 0, 0); }
#define SYNC_PRE()                                                              \
  do { __builtin_amdgcn_s_barrier();                                            \
       asm volatile("s_waitcnt lgkmcnt(0)" ::: "memory");                       \
       __builtin_amdgcn_s_setprio(1); } while (0)
#define SYNC_POST()                                                             \
  do { __builtin_amdgcn_s_setprio(0);                                           \
       __builtin_amdgcn_s_barrier(); } while (0)

template <typename OutT>
__global__ __launch_bounds__(512, 2)
void gemm256(const u16* __restrict__ Ag, const u16* __restrict__ Bg, int K,
             OutT* __restrict__ P0, OutT* __restrict__ P1, OutT* __restrict__ P2) {
    __shared__ u16 As[32768];   // [buf 2][half 2][rl 128][granule 8][8]  = 64KB
    __shared__ u16 Bs[32768];   // same layout                            = 64KB

    const int tid  = threadIdx.x;
    const int lane = tid & 63;
    const int wid  = tid >> 6;       // 0..7
    const int wm   = wid >> 2;       // wave row 0..1
    const int wn   = wid & 3;        // wave col 0..3
    const int lr   = lane & 15;
    const int lq   = lane >> 4;
    const int lr7  = lr & 7;

    const long bM  = (long)blockIdx.y * G_BM;
    const long bN0 = (long)blockIdx.x * G_BN;
    const int  KT  = K >> 6;         // 16

    // stage one half-tile (128 rows x 64 cols) of A or B for K-tile cc into its buffer slot
    auto stageA = [&](int cc, int h) {
#pragma unroll
        for (int l = 0; l < 2; l++) {
            const int G  = l * 512 + tid;
            const int rl = G >> 3;
            const int gk = (G & 7) ^ (rl & 7);
            const int r  = (rl & 63) + h * 64 + ((rl >> 6) << 7);  // rows: bit6 == h
            async_cp16(Ag + (bM + r) * K + cc * 64 + gk * 8,
                       &As[(((cc & 1) * 2 + h) << 13) + G * 8]);
        }
    };
    auto stageB = [&](int cc, int h) {
#pragma unroll
        for (int l = 0; l < 2; l++) {
            const int G  = l * 512 + tid;
            const int rl = G >> 3;
            const int gk = (G & 7) ^ (rl & 7);
            const int r  = (rl & 31) + h * 32 + ((rl >> 5) << 6);  // rows: bit5 == h
            async_cp16(Bg + (bN0 + r) * K + cc * 64 + gk * 8,
                       &Bs[(((cc & 1) * 2 + h) << 13) + G * 8]);
        }
    };

    const f32x4 zero = {0.f, 0.f, 0.f, 0.f};
    f32x4 acc[8][4];
#pragma unroll
    for (int i = 0; i < 8; i++)
#pragma unroll
        for (int j = 0; j < 4; j++) acc[i][j] = zero;

    // prologue: tile0 fully + first two halves of tile1 (issue order = retirement order)
    stageA(0, 0); stageB(0, 0); stageA(0, 1); stageB(0, 1);
    if (KT > 1) {
        stageA(1, 0); stageB(1, 0);
        asm volatile("s_waitcnt vmcnt(4)" ::: "memory");   // tile0 landed, tile1 A0/B0 in flight
    } else {
        asm volatile("s_waitcnt vmcnt(0)" ::: "memory");
    }
    __builtin_amdgcn_s_barrier();

    for (int c = 0; c < KT; ++c) {
        const int  p  = c & 1;
        const bool s1 = (c + 1 < KT);
        const bool s2 = (c + 2 < KT);
        bf16x8 av0[4][2], av1[4][2], bv0[2][2], bv1[2][2];
        // P1: quadrant (0,0)
        READ_A(av0, 0); READ_B(bv0, 0);
        if (s1) stageA(c + 1, 1);
        SYNC_PRE(); MFMA16(av0, bv0, 0, 0); SYNC_POST();
        // P2: quadrant (0,1)  (av0 retained in regs)
        READ_B(bv1, 1);
        if (s1) stageB(c + 1, 1);
        SYNC_PRE(); MFMA16(av0, bv1, 0, 1); SYNC_POST();
        // P3: quadrant (1,0)  (bv0 retained)
        READ_A(av1, 1);
        if (s2) stageA(c + 2, 0);
        SYNC_PRE(); MFMA16(av1, bv0, 1, 0); SYNC_POST();
        // P4: quadrant (1,1)  (av1, bv1 retained; no ds_reads)
        if (s2) {
            stageB(c + 2, 0);
            asm volatile("s_waitcnt vmcnt(4)" ::: "memory");  // tile c+1 fully landed
        } else if (s1) {
            asm volatile("s_waitcnt vmcnt(0)" ::: "memory");  // final drain before last tile
        }
        SYNC_PRE(); MFMA16(av1, bv1, 1, 1); SYNC_POST();
    }

    const int pl = (int)(bN0 >> 10);   // G_BN=256 divides 1024 -> whole block in one plane
    OutT* P = (pl == 0) ? P0 : ((pl == 1) ? P1 : P2);
    const int cn = (int)(bN0 & 1023);
#pragma unroll
    for (int i = 0; i < 8; i++) {
        const long m0 = bM + wm * 128 + i * 16 + lq * 4;
#pragma unroll
        for (int j = 0; j < 4; j++) {
            const int n = cn + wn * 64 + j * 16 + lr;
#pragma unroll
            for (int r = 0; r < 4; r++) {
                if constexpr (sizeof(OutT) == 2)
                    P[(m0 + r) * 1024 + n] = f2bf(acc[i][j][r]);
                else
                    P[(m0 + r) * 1024 + n] = acc[i][j][r];
            }
        }
    }
}

// ---------------------------------------------------------------- chunked scan
// h_t = f_t * h_{t-1} + silu(i_t)*(1-f_t),  f = sigmoid(f_pre); planes are bf16
__global__ __launch_bounds__(256) void scan_pass1(const u16* __restrict__ ip,
                                                  const u16* __restrict__ fp,
                                                  float* __restrict__ Fc,
                                                  float* __restrict__ Ic) {
    const int tid = blockIdx.x * 256 + threadIdx.x;  // B*NC*D/4 = 65536 threads
    const int d4  = tid & 255;                       // d/4
    const int c   = (tid >> 8) & (NC - 1);
    const int b   = tid >> 14;
    size_t base = ((size_t)(b * TT + c * CT) << 10) + (size_t)d4 * 4;
    float F[4] = {1.f, 1.f, 1.f, 1.f};
    float I[4] = {0.f, 0.f, 0.f, 0.f};
#pragma unroll 8
    for (int t = 0; t < CT; t++) {
        ushort4 fu = *(const ushort4*)(fp + base);
        ushort4 iu = *(const ushort4*)(ip + base);
        base += DD;
        const u16 fa[4] = {fu.x, fu.y, fu.z, fu.w};
        const u16 ia[4] = {iu.x, iu.y, iu.z, iu.w};
#pragma unroll
        for (int j = 0; j < 4; j++) {
            float f  = sigm(bf2f(fa[j]));
            float iv = bf2f(ia[j]);
            float v  = iv * sigm(iv) * (1.f - f);
            I[j] = fmaf(f, I[j], v);
            F[j] *= f;
        }
    }
    const size_t o = (((size_t)(b * NC + c)) << 10) + (size_t)d4 * 4;
    float4 vF = {F[0], F[1], F[2], F[3]};
    float4 vI = {I[0], I[1], I[2], I[3]};
    *(float4*)(Fc + o) = vF;
    *(float4*)(Ic + o) = vI;
}

// pass2: exclusive scan over the 64 chunks via in-wave Kogge-Stone.
__global__ __launch_bounds__(256) void scan_pass2(const float* __restrict__ Fc,
                                                  const float* __restrict__ Ic,
                                                  float* __restrict__ Hin) {
    const int gtid = blockIdx.x * 256 + threadIdx.x;   // B*D*64 = 262144 threads
    const int lane = gtid & 63;                        // chunk c
    const int w    = gtid >> 6;                        // wave id = (b,d)
    const int b    = w >> 10;
    const int d    = w & 1023;
    const int idx  = ((b * NC + lane) << 10) + d;
    float F = Fc[idx];
    float I = Ic[idx];
#pragma unroll
    for (int s = 1; s < 64; s <<= 1) {
        float Fp = __shfl_up(F, s, 64);
        float Ip = __shfl_up(I, s, 64);
        if (lane >= s) {
            I = fmaf(Ip, F, I);   // use pre-update F
            F *= Fp;
        }
    }
    float Hex = __shfl_up(I, 1, 64);
    if (lane == 0) Hex = 0.f;
    Hin[idx] = Hex;
}

__global__ __launch_bounds__(256) void scan_pass3(const u16* __restrict__ ip,
                                                  const u16* __restrict__ fp,
                                                  const float* __restrict__ Hin,
                                                  u16* __restrict__ hout) {
    const int tid = blockIdx.x * 256 + threadIdx.x;  // B*NC*D/4 = 65536 threads
    const int d4  = tid & 255;
    const int c   = (tid >> 8) & (NC - 1);
    const int b   = tid >> 14;
    size_t base = ((size_t)(b * TT + c * CT) << 10) + (size_t)d4 * 4;
    const size_t o = (((size_t)(b * NC + c)) << 10) + (size_t)d4 * 4;
    float4 hv = *(const float4*)(Hin + o);
    float h[4] = {hv.x, hv.y, hv.z, hv.w};
#pragma unroll 8
    for (int t = 0; t < CT; t++) {
        ushort4 fu = *(const ushort4*)(fp + base);
        ushort4 iu = *(const ushort4*)(ip + base);
        const u16 fa[4] = {fu.x, fu.y, fu.z, fu.w};
        const u16 ia[4] = {iu.x, iu.y, iu.z, iu.w};
        ushort4 ou;
        u16 oa[4];
#pragma unroll
        for (int j = 0; j < 4; j++) {
            float f  = sigm(bf2f(fa[j]));
            float iv = bf2f(ia[j]);
            float v  = iv * sigm(iv) * (1.f - f);
            h[j] = fmaf(f, h[j], v);
            oa[j] = f2bf(h[j]);
        }
        ou.x = oa[0]; ou.y = oa[1]; ou.z = oa[2]; ou.w = oa[3];
        *(ushort4*)(hout + base) = ou;
        base += DD;
    }
}

// ---------------------------------------------------------------- RMSNorm * swish(g)
__global__ __launch_bounds__(256) void rmsnorm_gate(const u16* hin,
                                                    const u16* __restrict__ g,
                                                    const float* __restrict__ w,
                                                    u16* oout) {
    const int row = blockIdx.x;
    const int t = threadIdx.x;
    const size_t base = ((size_t)row << 10) + t * 4;
    ushort4 hu = *(const ushort4*)(hin + base);
    float h0 = bf2f(hu.x), h1 = bf2f(hu.y), h2 = bf2f(hu.z), h3 = bf2f(hu.w);
    float ss = h0 * h0 + h1 * h1 + h2 * h2 + h3 * h3;
#pragma unroll
    for (int o = 32; o > 0; o >>= 1) ss += __shfl_down(ss, o);
    __shared__ float red[4];
    if ((t & 63) == 0) red[t >> 6] = ss;
    __syncthreads();
    const float tot = red[0] + red[1] + red[2] + red[3];
    const float rms = rsqrtf(tot * (1.f / 1024.f) + 1e-5f);
    ushort4 gu = *(const ushort4*)(g + base);
    float g0 = bf2f(gu.x), g1 = bf2f(gu.y), g2 = bf2f(gu.z), g3 = bf2f(gu.w);
    float4 wv = *(const float4*)(w + (size_t)t * 4);
    ushort4 ou;
    ou.x = f2bf(h0 * rms * wv.x * g0 * sigm(g0));
    ou.y = f2bf(h1 * rms * wv.y * g1 * sigm(g1));
    ou.z = f2bf(h2 * rms * wv.z * g2 * sigm(g2));
    ou.w = f2bf(h3 * rms * wv.w * g3 * sigm(g3));
    *(ushort4*)(oout + base) = ou;
}

// ---------------------------------------------------------------- launch
extern "C" void kernel_launch(void* const* d_in, const int* in_sizes, int n_in,
                              void* d_out, int out_size, void* d_ws, size_t ws_size,
                              hipStream_t stream) {
    const float* x  = (const float*)d_in[0];
    const float* Wi = (const float*)d_in[1];
    const float* Wf = (const float*)d_in[2];
    const float* Wg = (const float*)d_in[3];
    const float* Wo = (const float*)d_in[4];
    const float* nw = (const float*)d_in[5];
    float* out = (float*)d_out;

    const size_t MB = 1ull << 20;
    char* ws = (char*)d_ws;
    u16*   xo  = (u16*)(ws);              // 32MB: x_bf16, later h_bf16 then o_bf16
    u16*   Wb  = (u16*)(ws + 32 * MB);    // 8MB: [Wi;Wf;Wg;Wo] bf16, K-major rows
    u16*   Pi  = (u16*)(ws + 40 * MB);    // 32MB: i_pre bf16
    u16*   Pf  = (u16*)(ws + 72 * MB);    // 32MB: f_pre bf16
    float* Fc  = (float*)(ws + 104 * MB); // 1MB
    float* Ic  = Fc + BB * NC * DD;       // 1MB
    float* Hin = Ic + BB * NC * DD;       // 1MB
    u16*   g   = (u16*)d_out;             // g plane (bf16) parked in d_out until final GEMM

    conv_x_kernel<<<16384, 256, 0, stream>>>(x, xo);
    conv_w4_kernel<<<4096, 256, 0, stream>>>(Wi, Wf, Wg, Wo, Wb);
    // i_pre / f_pre / g in one GEMM: N=3072
    gemm256<u16><<<dim3(12, 64), 512, 0, stream>>>(xo, Wb, 1024, Pi, Pf, g);
    scan_pass1<<<256, 256, 0, stream>>>(Pi, Pf, Fc, Ic);
    scan_pass2<<<1024, 256, 0, stream>>>(Fc, Ic, Hin);
    scan_pass3<<<256, 256, 0, stream>>>(Pi, Pf, Hin, xo);
    rmsnorm_gate<<<16384, 256, 0, stream>>>(xo, g, nw, xo);
    // out = o @ Wo^T
    gemm256<float><<<dim3(4, 64), 512, 0, stream>>>(xo, Wb + 3ull * 1024 * 1024, 1024,
                                                    out, out, out);
}